// Round 5
// baseline (141.689 us; speedup 1.0000x reference)
//
#include <hip/hip_runtime.h>
#include <hip/hip_bf16.h>

typedef __attribute__((ext_vector_type(8))) short short8;
typedef __attribute__((ext_vector_type(16))) float f32x16;
typedef __fp16 h2 __attribute__((ext_vector_type(2)));
typedef unsigned short ushort_t;

#define DEVFN static __device__ __forceinline__
#define MFMA32 __builtin_amdgcn_mfma_f32_32x32x16_bf16

DEVFN float bf2f(unsigned short u){
  union { unsigned int i; float f; } v; v.i = ((unsigned int)u) << 16; return v.f;
}
DEVFN unsigned short f2bf(float f){
  unsigned int u = __float_as_uint(f);
  unsigned int r = u + 0x7FFFu + ((u >> 16) & 1u);
  return (unsigned short)(r >> 16);
}
DEVFN unsigned int pkbf(float lo, float hi){
  __hip_bfloat162 h = __float22bfloat162_rn(make_float2(lo, hi));
  return *reinterpret_cast<unsigned int*>(&h);
}
DEVFN h2 pkrtz(float a, float b){ return __builtin_amdgcn_cvt_pkrtz(a, b); }
DEVFN h2 u2h(unsigned int u){ union { unsigned int u; h2 h; } v; v.u = u; return v.h; }
#if __has_builtin(__builtin_amdgcn_fdot2)
DEVFN float fdot2(h2 a, h2 b, float c){ return __builtin_amdgcn_fdot2(a, b, c, false); }
#else
DEVFN float fdot2(h2 a, h2 b, float c){ return c + (float)a[0]*(float)b[0] + (float)a[1]*(float)b[1]; }
#endif
DEVFN float tanh_fast(float x){
  float t = __builtin_amdgcn_exp2f(x * 2.885390081777926815f);
  return 1.0f - 2.0f * __builtin_amdgcn_rcpf(t + 1.0f);
}
// shared A/B K-slot mapping for 32x32x16 MFMA fragments
DEVFN int kmap(int h, int j){ return 4*h + (j & 3) + 8*(j >> 2); }

// ---------------- weight bake ----------------
// wfrag (hw): ((f*4 + gq)*2 + nh)*3072 + (l*2 + nt)*512 + lane*8 + j
//   n = nh*64 + nt*32 + (lane&31) ; g(j) = gq*16 + kmap(lane>>5, j)
__global__ void bake_w0(const float* __restrict__ wx0, const float* __restrict__ wy0,
                        ushort_t* __restrict__ wfrag){
  int slot = blockIdx.x * 256 + threadIdx.x;      // < 196608
  int lane = slot & 63;
  int q = slot >> 6;            // < 3072
  int blk = q % 6; int q2 = q / 6;
  int l = blk >> 1, nt = blk & 1;
  int nh = q2 & 1; int gq = (q2 >> 1) & 3; int f = q2 >> 3;
  int h = lane >> 5;
  int k = nt*32 + (lane & 31);
  const float* w = nh ? wy0 : wx0;
  unsigned int pk[4];
#pragma unroll
  for (int jj = 0; jj < 4; ++jj){
    int g0 = gq*16 + kmap(h, 2*jj);
    int g1 = gq*16 + kmap(h, 2*jj + 1);
    unsigned int b0 = f2bf(w[((k*64 + f)*64 + g0)*3 + l]);
    unsigned int b1 = f2bf(w[((k*64 + f)*64 + g1)*3 + l]);
    pk[jj] = b0 | (b1 << 16);
  }
  *reinterpret_cast<uint4*>(wfrag + (size_t)slot * 8) = make_uint4(pk[0], pk[1], pk[2], pk[3]);
}

__global__ void bake_wh(const float* __restrict__ wxh, const float* __restrict__ wyh,
                        ushort_t* __restrict__ whfrag){
  int slot = blockIdx.x * 256 + threadIdx.x;      // < 2048
  int lane = slot & 63;
  int q = slot >> 6;
  int nt = q & 1; q >>= 1;
  int c  = q & 3; q >>= 2;
  int path = q & 1; int layer = q >> 1;
  const float* w = path ? wyh : wxh;
  int n = nt*32 + (lane & 31);
  int h = lane >> 5;
  unsigned int pk[4];
#pragma unroll
  for (int jj = 0; jj < 4; ++jj){
    int k0 = c*16 + kmap(h, 2*jj);
    int k1 = c*16 + kmap(h, 2*jj + 1);
    unsigned int b0 = f2bf(w[layer*4096 + k0*64 + n]);
    unsigned int b1 = f2bf(w[layer*4096 + k1*64 + n]);
    pk[jj] = b0 | (b1 << 16);
  }
  *reinterpret_cast<uint4*>(whfrag + (size_t)slot * 8) = make_uint4(pk[0], pk[1], pk[2], pk[3]);
}

__global__ void bake_wf(const float* __restrict__ wxf, const float* __restrict__ wyf,
                        ushort_t* __restrict__ wffrag){
  int slot = blockIdx.x * 256 + threadIdx.x;      // < 3072
  int lane = slot & 63;
  int q = slot >> 6;            // < 48
  int ntf = q % 6;
  int q2 = q / 6;
  int c = q2 & 3; int path = q2 >> 2;
  const float* w = path ? wyf : wxf;
  int n = ntf*32 + (lane & 31);
  int lw = n >> 6, fw = n & 63;
  int h = lane >> 5;
  unsigned int pk[4];
#pragma unroll
  for (int jj = 0; jj < 4; ++jj){
    int k0 = c*16 + kmap(h, 2*jj);
    int k1 = c*16 + kmap(h, 2*jj + 1);
    unsigned int b0 = f2bf(w[(lw*64 + fw)*64 + k0]);
    unsigned int b1 = f2bf(w[(lw*64 + fw)*64 + k1]);
    pk[jj] = b0 | (b1 << 16);
  }
  *reinterpret_cast<uint4*>(wffrag + (size_t)slot * 8) = make_uint4(pk[0], pk[1], pk[2], pk[3]);
}

// y -> padded f16: y2h[p][f][12] halves, (s0..s8, 0,0,0)
__global__ void bake_y(const float* __restrict__ y, ushort_t* __restrict__ y2h){
  int idx = blockIdx.x * 256 + threadIdx.x;       // dword index < 3,145,728
  int d = idx % 6; int pf = idx / 6;
  const float* src = y + (size_t)pf * 9;
  int s0 = d*2, s1 = d*2 + 1;
  float v0 = (s0 < 9) ? src[s0] : 0.f;
  float v1 = (s1 < 9) ? src[s1] : 0.f;
  h2 pk = pkrtz(v0, v1);
  reinterpret_cast<unsigned int*>(y2h)[(size_t)pf*6 + d] =
      *reinterpret_cast<unsigned int*>(&pk);
}

// ---------------- main fused GEMM (barrier-free waves) ----------------
// Grid 512 WG x 256 thr; WG = (pt<128: 64 pts) x nh(2) x fh(2); wave = gq quarter.
// Per wave: 2 m-tiles x 2 n-tiles, f-half (32 steps), all l. All operands in regs.
struct BSet { uint4 b[6]; };
struct YSet { uint2 q0, q1; unsigned int d; };
union U4 { uint4 u; short8 s; };

__global__ __launch_bounds__(256, 2)
void gemm5(const float* __restrict__ x, const float* __restrict__ y,
           const ushort_t* __restrict__ y2h, const ushort_t* __restrict__ wfrag,
           float* __restrict__ mixp){
  __shared__ float red[2][64][64];

  const int bid = blockIdx.x;
  const int id = (bid & 7)*64 + (bid >> 3);       // XCD-chunked bijection (512 = 8*64)
  const int fh = id & 1, nh = (id >> 1) & 1, pt = id >> 2;
  const int pbase = pt * 64;
  const int f0 = fh * 32;

  const int t = threadIdx.x, lane = t & 63, gq = t >> 6;
  const int h = lane >> 5, pr = lane & 31;

  // ---- xg init: 2 m-rows x 8 g, packed h2 pairs (s0,s1)(s2,s3)(s4,s5)(s6,s7)(s8,0) ----
  h2 xg[2][8][5];
#pragma unroll
  for (int r = 0; r < 2; ++r){
    const int p = pbase + r*32 + pr;
#pragma unroll
    for (int j = 0; j < 8; ++j){
      const int g = gq*16 + kmap(h, j);
      const float* xp = x + (size_t)p*576 + g*9;
      const float* yp = y + (size_t)p*576 + g*9;
      float x1 = xp[1], x2 = xp[2], x3 = xp[3];
      float y0 = yp[0], y1 = yp[1], y2 = yp[2], y3 = yp[3];
      float gate = (x2*y3 - x3*y2)*y0 + (x3*y1 - x1*y3)*y1 + (x1*y2 - x2*y1)*y2;
      xg[r][j][0] = pkrtz(xp[0]*gate, x1*gate);
      xg[r][j][1] = pkrtz(x2*gate, x3*gate);
      xg[r][j][2] = pkrtz(xp[4]*gate, xp[5]*gate);
      xg[r][j][3] = pkrtz(xp[6]*gate, xp[7]*gate);
      xg[r][j][4] = pkrtz(xp[8]*gate, 0.f);
    }
  }

  f32x16 acc00, acc01, acc10, acc11;
#pragma unroll
  for (int e = 0; e < 16; ++e){ acc00[e]=0.f; acc01[e]=0.f; acc10[e]=0.f; acc11[e]=0.f; }

  const ushort_t* wt = wfrag + (size_t)(gq*2 + nh)*3072 + (size_t)lane*8;
  const ushort_t* yb0 = y2h + (size_t)(pbase + pr)*768 + f0*12;
  const ushort_t* yb1 = yb0 + 32*768;

  auto ldB = [&](int f, BSet& B){
    const ushort_t* p0 = wt + (size_t)f * 24576;
#pragma unroll
    for (int i = 0; i < 6; ++i) B.b[i] = *reinterpret_cast<const uint4*>(p0 + i*512);
  };
  auto ldY = [&](int s, YSet& Y0, YSet& Y1){
    const ushort_t* r0 = yb0 + s*12;
    Y0.q0 = *reinterpret_cast<const uint2*>(r0);
    Y0.q1 = *reinterpret_cast<const uint2*>(r0 + 4);
    Y0.d  = *reinterpret_cast<const unsigned int*>(r0 + 8);
    const ushort_t* r1 = yb1 + s*12;
    Y1.q0 = *reinterpret_cast<const uint2*>(r1);
    Y1.q1 = *reinterpret_cast<const uint2*>(r1 + 4);
    Y1.d  = *reinterpret_cast<const unsigned int*>(r1 + 8);
  };

#define AGEN_MFMA(R, Y, B) do{                                                       \
    const unsigned int yu01 = (Y).q0.x;                                              \
    h2 y0m = u2h(yu01 & 0xFFFFu);                                                    \
    h2 y1m = u2h(yu01 & 0xFFFF0000u);                                                \
    h2 y23 = u2h((Y).q0.y), y45 = u2h((Y).q1.x), y67 = u2h((Y).q1.y), y8p = u2h((Y).d); \
    float a0[8], a1[8], a2[8];                                                       \
    _Pragma("unroll")                                                                \
    for (int j = 0; j < 8; ++j){                                                     \
      a0[j] = fdot2(xg[R][j][0], y0m, 0.f);                                          \
      a1[j] = fdot2(xg[R][j][1], y23, fdot2(xg[R][j][0], y1m, 0.f));                 \
      a2[j] = fdot2(xg[R][j][4], y8p, fdot2(xg[R][j][3], y67, fdot2(xg[R][j][2], y45, 0.f))); \
    }                                                                                \
    U4 fA0, fA1, fA2;                                                                \
    fA0.u = make_uint4(pkbf(a0[0],a0[1]), pkbf(a0[2],a0[3]), pkbf(a0[4],a0[5]), pkbf(a0[6],a0[7])); \
    fA1.u = make_uint4(pkbf(a1[0],a1[1]), pkbf(a1[2],a1[3]), pkbf(a1[4],a1[5]), pkbf(a1[6],a1[7])); \
    fA2.u = make_uint4(pkbf(a2[0],a2[1]), pkbf(a2[2],a2[3]), pkbf(a2[4],a2[5]), pkbf(a2[6],a2[7])); \
    U4 b0, b1, b2, b3, b4, b5;                                                       \
    b0.u = (B).b[0]; b1.u = (B).b[1]; b2.u = (B).b[2];                               \
    b3.u = (B).b[3]; b4.u = (B).b[4]; b5.u = (B).b[5];                               \
    acc##R##0 = MFMA32(fA0.s, b0.s, acc##R##0, 0, 0, 0);                             \
    acc##R##1 = MFMA32(fA0.s, b1.s, acc##R##1, 0, 0, 0);                             \
    acc##R##0 = MFMA32(fA1.s, b2.s, acc##R##0, 0, 0, 0);                             \
    acc##R##1 = MFMA32(fA1.s, b3.s, acc##R##1, 0, 0, 0);                             \
    acc##R##0 = MFMA32(fA2.s, b4.s, acc##R##0, 0, 0, 0);                             \
    acc##R##1 = MFMA32(fA2.s, b5.s, acc##R##1, 0, 0, 0);                             \
  }while(0)

  BSet Ba, Bb; YSet Ya0, Ya1, Yb0, Yb1;
  ldB(f0 + 0, Ba); ldY(0, Ya0, Ya1);
  ldB(f0 + 1, Bb); ldY(1, Yb0, Yb1);

#pragma unroll 1
  for (int s = 0; s < 32; s += 2){
    AGEN_MFMA(0, Ya0, Ba);
    AGEN_MFMA(1, Ya1, Ba);
    const int s2 = (s + 2 < 32) ? s + 2 : 31;
    ldB(f0 + s2, Ba); ldY(s2, Ya0, Ya1);
    AGEN_MFMA(0, Yb0, Bb);
    AGEN_MFMA(1, Yb1, Bb);
    const int s3 = (s + 3 < 32) ? s + 3 : 31;
    ldB(f0 + s3, Bb); ldY(s3, Yb0, Yb1);
  }
#undef AGEN_MFMA

  // ---- in-WG reduction over gq (3 barriers total) ----
  if (gq >= 2){
#pragma unroll
    for (int e = 0; e < 16; ++e){
      red[gq-2][ 0+e][lane] = acc00[e];
      red[gq-2][16+e][lane] = acc01[e];
      red[gq-2][32+e][lane] = acc10[e];
      red[gq-2][48+e][lane] = acc11[e];
    }
  }
  __syncthreads();
  if (gq < 2){
#pragma unroll
    for (int e = 0; e < 16; ++e){
      acc00[e] += red[gq][ 0+e][lane];
      acc01[e] += red[gq][16+e][lane];
      acc10[e] += red[gq][32+e][lane];
      acc11[e] += red[gq][48+e][lane];
    }
  }
  __syncthreads();
  if (gq == 1){
#pragma unroll
    for (int e = 0; e < 16; ++e){
      red[0][ 0+e][lane] = acc00[e];
      red[0][16+e][lane] = acc01[e];
      red[0][32+e][lane] = acc10[e];
      red[0][48+e][lane] = acc11[e];
    }
  }
  __syncthreads();
  if (gq == 0){
    float* mp = mixp + (size_t)fh * 1048576;
#pragma unroll
    for (int e = 0; e < 16; ++e){
      float v00 = acc00[e] + red[0][ 0+e][lane];
      float v01 = acc01[e] + red[0][16+e][lane];
      float v10 = acc10[e] + red[0][32+e][lane];
      float v11 = acc11[e] + red[0][48+e][lane];
      int rowm = (e & 3) + 8*(e >> 2) + 4*h;
      mp[(size_t)(pbase + rowm)*128      + nh*64 + pr]      = v00;
      mp[(size_t)(pbase + rowm)*128      + nh*64 + 32 + pr] = v01;
      mp[(size_t)(pbase + 32 + rowm)*128 + nh*64 + pr]      = v10;
      mp[(size_t)(pbase + 32 + rowm)*128 + nh*64 + 32 + pr] = v11;
    }
  }
}

// ---------------- MLP + final einsum + epilogue ----------------
__global__ __launch_bounds__(256, 1)
void mlp_final(const float* __restrict__ x, const float* __restrict__ y,
               const ushort_t* __restrict__ whfrag,
               const ushort_t* __restrict__ wffrag,
               const float* __restrict__ mixp, float* __restrict__ out){
  extern __shared__ char ldsm[];
  ushort_t* hw = (ushort_t*)ldsm;
  const int t = threadIdx.x;
  const long pbase = (long)blockIdx.x * 32;

  {  // load mix = sum of 2 partials -> act buf0 (bf16)
    int p = t >> 3, n0 = (t & 7) * 16;
    const float* src = mixp + (pbase + p)*128 + n0;
    int path = n0 >> 6, nn = n0 & 63;
    ushort_t* dst = hw + (path*2)*2176 + p*68 + nn;
#pragma unroll
    for (int q2 = 0; q2 < 16; ++q2){
      float v = src[q2] + src[q2 + 1048576];
      dst[q2] = f2bf(v);
    }
  }
  __syncthreads();

  const int w = t >> 6, lane = t & 63;
  const int path = w >> 1, ntw = w & 1;
  const int prow = lane & 31, h = lane >> 5;
  int cur = 0;

#pragma unroll
  for (int layer = 0; layer < 2; ++layer){
    const ushort_t* act = hw + (path*2 + cur)*2176;
    f32x16 acc;
#pragma unroll
    for (int r = 0; r < 16; ++r) acc[r] = 0.f;
#pragma unroll
    for (int c = 0; c < 4; ++c){
      int ab = prow*68 + c*16 + 4*h;
      ushort4 lo = *(const ushort4*)&act[ab];
      ushort4 hi = *(const ushort4*)&act[ab + 8];
      short8 av; av[0]=lo.x; av[1]=lo.y; av[2]=lo.z; av[3]=lo.w;
      av[4]=hi.x; av[5]=hi.y; av[6]=hi.z; av[7]=hi.w;
      short8 bv = *(const short8*)(whfrag + ((((layer*2 + path)*4 + c)*2 + ntw)*512 + lane*8));
      acc = MFMA32(av, bv, acc, 0, 0, 0);
    }
    ushort_t* nact = hw + (path*2 + (cur ^ 1))*2176;
#pragma unroll
    for (int r = 0; r < 16; ++r){
      int p = (r & 3) + 8*(r >> 2) + 4*h;
      nact[p*68 + ntw*32 + prow] = f2bf(tanh_fast(acc[r]));
    }
    cur ^= 1;
    __syncthreads();
  }

  {  // final einsum: o[p][n=l*64+f], N=192 -> each wave 3 n-tiles
    const ushort_t* act = hw + (path*2 + cur)*2176;
    ushort_t* ob = hw + 8704 + path*6272;
#pragma unroll
    for (int e = 0; e < 3; ++e){
      int ntf = ntw*3 + e;
      f32x16 acc;
#pragma unroll
      for (int r = 0; r < 16; ++r) acc[r] = 0.f;
#pragma unroll
      for (int c = 0; c < 4; ++c){
        int ab = prow*68 + c*16 + 4*h;
        ushort4 lo = *(const ushort4*)&act[ab];
        ushort4 hi = *(const ushort4*)&act[ab + 8];
        short8 av; av[0]=lo.x; av[1]=lo.y; av[2]=lo.z; av[3]=lo.w;
        av[4]=hi.x; av[5]=hi.y; av[6]=hi.z; av[7]=hi.w;
        short8 bv = *(const short8*)(wffrag + (((path*4 + c)*6 + ntf)*512 + lane*8));
        acc = MFMA32(av, bv, acc, 0, 0, 0);
      }
#pragma unroll
      for (int r = 0; r < 16; ++r){
        int p = (r & 3) + 8*(r >> 2) + 4*h;
        ob[p*196 + ntf*32 + prow] = f2bf(tanh_fast(acc[r]));
      }
    }
  }
  __syncthreads();

  const ushort_t* oxb = hw + 8704;
  const ushort_t* oyb = hw + 8704 + 6272;
#pragma unroll 1
  for (int rep = 0; rep < 8; ++rep){
    int idx = t + rep*256;
    int p = idx >> 6, fq = idx & 63;
    const float* xr = x + ((pbase + p)*64 + fq)*9;
    const float* yr = y + ((pbase + p)*64 + fq)*9;
    float xv[9], yv[9];
#pragma unroll
    for (int s = 0; s < 9; ++s){ xv[s] = xr[s]; yv[s] = yr[s]; }
    float c0 = xv[2]*yv[3] - xv[3]*yv[2];
    float c1 = xv[3]*yv[1] - xv[1]*yv[3];
    float c2 = xv[1]*yv[2] - xv[2]*yv[1];
    float gate = c0*yv[0] + c1*yv[1] + c2*yv[2];
    float ox0 = bf2f(oxb[p*196 + fq]);
    float ox1 = bf2f(oxb[p*196 + 64 + fq]);
    float ox2 = bf2f(oxb[p*196 + 128 + fq]);
    float oy0 = bf2f(oyb[p*196 + fq]);
    float oy1 = bf2f(oyb[p*196 + 64 + fq]);
    float oy2 = bf2f(oyb[p*196 + 128 + fq]);
    float* orow = out + ((pbase + p)*64 + fq)*9;
    orow[0] = ox0*xv[0]*gate + oy0*yv[0];
#pragma unroll
    for (int s = 1; s < 4; ++s) orow[s] = ox1*xv[s]*gate + oy1*yv[s];
#pragma unroll
    for (int s = 4; s < 9; ++s) orow[s] = ox2*xv[s]*gate + oy2*yv[s];
  }
}

extern "C" void kernel_launch(void* const* d_in, const int* in_sizes, int n_in,
                              void* d_out, int out_size, void* d_ws, size_t ws_size,
                              hipStream_t stream){
  (void)in_sizes; (void)n_in; (void)out_size; (void)ws_size;
  const float* x   = (const float*)d_in[0];
  const float* y   = (const float*)d_in[1];
  const float* wx0 = (const float*)d_in[2];
  const float* wy0 = (const float*)d_in[3];
  const float* wxh = (const float*)d_in[4];
  const float* wyh = (const float*)d_in[5];
  const float* wxf = (const float*)d_in[6];
  const float* wyf = (const float*)d_in[7];
  float* out = (float*)d_out;
  char* ws = (char*)d_ws;
  ushort_t* wfrag  = (ushort_t*)(ws);              //  3,145,728 B
  ushort_t* whfrag = (ushort_t*)(ws + 3145728);    //     32,768 B
  ushort_t* wffrag = (ushort_t*)(ws + 3178496);    //     49,152 B
  ushort_t* y2h    = (ushort_t*)(ws + 3227648);    // 12,582,912 B
  float* mixp      = (float*)(ws + 15810560);      // 2 x 4,194,304 B

  (void)hipFuncSetAttribute((const void*)mlp_final,
        hipFuncAttributeMaxDynamicSharedMemorySize, 43520);

  hipLaunchKernelGGL(bake_w0, dim3(768),   dim3(256), 0, stream, wx0, wy0, wfrag);
  hipLaunchKernelGGL(bake_wh, dim3(8),     dim3(256), 0, stream, wxh, wyh, whfrag);
  hipLaunchKernelGGL(bake_wf, dim3(12),    dim3(256), 0, stream, wxf, wyf, wffrag);
  hipLaunchKernelGGL(bake_y,  dim3(12288), dim3(256), 0, stream, y, y2h);
  hipLaunchKernelGGL(gemm5,   dim3(512),   dim3(256), 0, stream, x, y, y2h, wfrag, mixp);
  hipLaunchKernelGGL(mlp_final, dim3(256), dim3(256), 42496, stream, x, y, whfrag, wffrag, mixp, out);
}

// Round 6
// 122.096 us; speedup vs baseline: 1.1605x; 1.1605x over previous
//
#include <hip/hip_runtime.h>
#include <hip/hip_bf16.h>

typedef __attribute__((ext_vector_type(8))) short short8;
typedef __attribute__((ext_vector_type(16))) float f32x16;
typedef __fp16 h2 __attribute__((ext_vector_type(2)));
typedef unsigned short ushort_t;

#define DEVFN static __device__ __forceinline__
#define MFMA32 __builtin_amdgcn_mfma_f32_32x32x16_bf16

DEVFN float bf2f(unsigned short u){
  union { unsigned int i; float f; } v; v.i = ((unsigned int)u) << 16; return v.f;
}
DEVFN unsigned short f2bf(float f){
  unsigned int u = __float_as_uint(f);
  unsigned int r = u + 0x7FFFu + ((u >> 16) & 1u);
  return (unsigned short)(r >> 16);
}
DEVFN unsigned int pkbf(float lo, float hi){
  __hip_bfloat162 h = __float22bfloat162_rn(make_float2(lo, hi));
  return *reinterpret_cast<unsigned int*>(&h);
}
DEVFN h2 pkrtz(float a, float b){ return __builtin_amdgcn_cvt_pkrtz(a, b); }
DEVFN h2 u2h(unsigned int u){ union { unsigned int u; h2 h; } v; v.u = u; return v.h; }
#if __has_builtin(__builtin_amdgcn_fdot2)
DEVFN float fdot2(h2 a, h2 b, float c){ return __builtin_amdgcn_fdot2(a, b, c, false); }
#else
DEVFN float fdot2(h2 a, h2 b, float c){ return c + (float)a[0]*(float)b[0] + (float)a[1]*(float)b[1]; }
#endif
DEVFN float tanh_fast(float x){
  float t = __builtin_amdgcn_exp2f(x * 2.885390081777926815f);
  return 1.0f - 2.0f * __builtin_amdgcn_rcpf(t + 1.0f);
}
// shared A/B K-slot mapping for 32x32x16 MFMA fragments
DEVFN int kmap(int h, int j){ return 4*h + (j & 3) + 8*(j >> 2); }

// ---------------- weight bake ----------------
// wfrag (hw): ((f*4 + gq)*2 + nh)*3072 + (l*2 + nt)*512 + lane*8 + j
//   n = nh*64 + nt*32 + (lane&31) ; g(j) = gq*16 + kmap(lane>>5, j)
__global__ void bake_w0(const float* __restrict__ wx0, const float* __restrict__ wy0,
                        ushort_t* __restrict__ wfrag){
  int slot = blockIdx.x * 256 + threadIdx.x;      // < 196608
  int lane = slot & 63;
  int q = slot >> 6;            // < 3072
  int blk = q % 6; int q2 = q / 6;
  int l = blk >> 1, nt = blk & 1;
  int nh = q2 & 1; int gq = (q2 >> 1) & 3; int f = q2 >> 3;
  int h = lane >> 5;
  int k = nt*32 + (lane & 31);
  const float* w = nh ? wy0 : wx0;
  unsigned int pk[4];
#pragma unroll
  for (int jj = 0; jj < 4; ++jj){
    int g0 = gq*16 + kmap(h, 2*jj);
    int g1 = gq*16 + kmap(h, 2*jj + 1);
    unsigned int b0 = f2bf(w[((k*64 + f)*64 + g0)*3 + l]);
    unsigned int b1 = f2bf(w[((k*64 + f)*64 + g1)*3 + l]);
    pk[jj] = b0 | (b1 << 16);
  }
  *reinterpret_cast<uint4*>(wfrag + (size_t)slot * 8) = make_uint4(pk[0], pk[1], pk[2], pk[3]);
}

__global__ void bake_wh(const float* __restrict__ wxh, const float* __restrict__ wyh,
                        ushort_t* __restrict__ whfrag){
  int slot = blockIdx.x * 256 + threadIdx.x;      // < 2048
  int lane = slot & 63;
  int q = slot >> 6;
  int nt = q & 1; q >>= 1;
  int c  = q & 3; q >>= 2;
  int path = q & 1; int layer = q >> 1;
  const float* w = path ? wyh : wxh;
  int n = nt*32 + (lane & 31);
  int h = lane >> 5;
  unsigned int pk[4];
#pragma unroll
  for (int jj = 0; jj < 4; ++jj){
    int k0 = c*16 + kmap(h, 2*jj);
    int k1 = c*16 + kmap(h, 2*jj + 1);
    unsigned int b0 = f2bf(w[layer*4096 + k0*64 + n]);
    unsigned int b1 = f2bf(w[layer*4096 + k1*64 + n]);
    pk[jj] = b0 | (b1 << 16);
  }
  *reinterpret_cast<uint4*>(whfrag + (size_t)slot * 8) = make_uint4(pk[0], pk[1], pk[2], pk[3]);
}

__global__ void bake_wf(const float* __restrict__ wxf, const float* __restrict__ wyf,
                        ushort_t* __restrict__ wffrag){
  int slot = blockIdx.x * 256 + threadIdx.x;      // < 3072
  int lane = slot & 63;
  int q = slot >> 6;            // < 48
  int ntf = q % 6;
  int q2 = q / 6;
  int c = q2 & 3; int path = q2 >> 2;
  const float* w = path ? wyf : wxf;
  int n = ntf*32 + (lane & 31);
  int lw = n >> 6, fw = n & 63;
  int h = lane >> 5;
  unsigned int pk[4];
#pragma unroll
  for (int jj = 0; jj < 4; ++jj){
    int k0 = c*16 + kmap(h, 2*jj);
    int k1 = c*16 + kmap(h, 2*jj + 1);
    unsigned int b0 = f2bf(w[(lw*64 + fw)*64 + k0]);
    unsigned int b1 = f2bf(w[(lw*64 + fw)*64 + k1]);
    pk[jj] = b0 | (b1 << 16);
  }
  *reinterpret_cast<uint4*>(wffrag + (size_t)slot * 8) = make_uint4(pk[0], pk[1], pk[2], pk[3]);
}

// y -> padded f16: y2h[p][f][12] halves, (s0..s8, 0,0,0)
__global__ void bake_y(const float* __restrict__ y, ushort_t* __restrict__ y2h){
  int idx = blockIdx.x * 256 + threadIdx.x;       // dword index < 3,145,728
  int d = idx % 6; int pf = idx / 6;
  const float* src = y + (size_t)pf * 9;
  int s0 = d*2, s1 = d*2 + 1;
  float v0 = (s0 < 9) ? src[s0] : 0.f;
  float v1 = (s1 < 9) ? src[s1] : 0.f;
  h2 pk = pkrtz(v0, v1);
  reinterpret_cast<unsigned int*>(y2h)[(size_t)pf*6 + d] =
      *reinterpret_cast<unsigned int*>(&pk);
}

// ---------------- main fused GEMM (barrier-free waves) ----------------
// Grid 512 WG x 256 thr; WG = (pt<128: 64 pts) x nh(2) x fh(2); wave = gq quarter.
// Per wave: 2 m-tiles x 2 n-tiles, f-half (32 steps), all l. All operands in regs.
// NOTE: no min-waves in launch_bounds -> allocator may use up to ~512 unified
// VGPR+AGPR, which fits the ~270 live regs with ZERO spill (round-5 spilled at
// the 128-cap: WRITE_SIZE 38.9MB vs 8MB real output).
struct BSet { uint4 b[6]; };
struct YSet { uint2 q0, q1; unsigned int d; };
union U4 { uint4 u; short8 s; };

__global__ __launch_bounds__(256)
void gemm5(const float* __restrict__ x, const float* __restrict__ y,
           const ushort_t* __restrict__ y2h, const ushort_t* __restrict__ wfrag,
           float* __restrict__ mixp){
  __shared__ float red[2][64][64];

  const int bid = blockIdx.x;
  const int id = (bid & 7)*64 + (bid >> 3);       // XCD-chunked bijection (512 = 8*64)
  const int fh = id & 1, nh = (id >> 1) & 1, pt = id >> 2;
  const int pbase = pt * 64;
  const int f0 = fh * 32;

  const int t = threadIdx.x, lane = t & 63, gq = t >> 6;
  const int h = lane >> 5, pr = lane & 31;

  // ---- xg init: 2 m-rows x 8 g, packed h2 pairs ----
  h2 xg[2][8][5];
#pragma unroll
  for (int r = 0; r < 2; ++r){
    const int p = pbase + r*32 + pr;
#pragma unroll
    for (int j = 0; j < 8; ++j){
      const int g = gq*16 + kmap(h, j);
      const float* xp = x + (size_t)p*576 + g*9;
      const float* yp = y + (size_t)p*576 + g*9;
      float x1 = xp[1], x2 = xp[2], x3 = xp[3];
      float y0 = yp[0], y1 = yp[1], y2 = yp[2], y3 = yp[3];
      float gate = (x2*y3 - x3*y2)*y0 + (x3*y1 - x1*y3)*y1 + (x1*y2 - x2*y1)*y2;
      xg[r][j][0] = pkrtz(xp[0]*gate, x1*gate);
      xg[r][j][1] = pkrtz(x2*gate, x3*gate);
      xg[r][j][2] = pkrtz(xp[4]*gate, xp[5]*gate);
      xg[r][j][3] = pkrtz(xp[6]*gate, xp[7]*gate);
      xg[r][j][4] = pkrtz(xp[8]*gate, 0.f);
    }
  }

  f32x16 acc00, acc01, acc10, acc11;
#pragma unroll
  for (int e = 0; e < 16; ++e){ acc00[e]=0.f; acc01[e]=0.f; acc10[e]=0.f; acc11[e]=0.f; }

  const ushort_t* wt = wfrag + (size_t)(gq*2 + nh)*3072 + (size_t)lane*8;
  const ushort_t* yb0 = y2h + (size_t)(pbase + pr)*768 + f0*12;
  const ushort_t* yb1 = yb0 + 32*768;

  auto ldB = [&](int f, BSet& B){
    const ushort_t* p0 = wt + (size_t)f * 24576;
#pragma unroll
    for (int i = 0; i < 6; ++i) B.b[i] = *reinterpret_cast<const uint4*>(p0 + i*512);
  };
  auto ldY = [&](int s, YSet& Y0, YSet& Y1){
    const ushort_t* r0 = yb0 + s*12;
    Y0.q0 = *reinterpret_cast<const uint2*>(r0);
    Y0.q1 = *reinterpret_cast<const uint2*>(r0 + 4);
    Y0.d  = *reinterpret_cast<const unsigned int*>(r0 + 8);
    const ushort_t* r1 = yb1 + s*12;
    Y1.q0 = *reinterpret_cast<const uint2*>(r1);
    Y1.q1 = *reinterpret_cast<const uint2*>(r1 + 4);
    Y1.d  = *reinterpret_cast<const unsigned int*>(r1 + 8);
  };

#define AGEN_MFMA(R, Y, B) do{                                                       \
    const unsigned int yu01 = (Y).q0.x;                                              \
    h2 y0m = u2h(yu01 & 0xFFFFu);                                                    \
    h2 y1m = u2h(yu01 & 0xFFFF0000u);                                                \
    h2 y23 = u2h((Y).q0.y), y45 = u2h((Y).q1.x), y67 = u2h((Y).q1.y), y8p = u2h((Y).d); \
    float a0[8], a1[8], a2[8];                                                       \
    _Pragma("unroll")                                                                \
    for (int j = 0; j < 8; ++j){                                                     \
      a0[j] = fdot2(xg[R][j][0], y0m, 0.f);                                          \
      a1[j] = fdot2(xg[R][j][1], y23, fdot2(xg[R][j][0], y1m, 0.f));                 \
      a2[j] = fdot2(xg[R][j][4], y8p, fdot2(xg[R][j][3], y67, fdot2(xg[R][j][2], y45, 0.f))); \
    }                                                                                \
    U4 fA0, fA1, fA2;                                                                \
    fA0.u = make_uint4(pkbf(a0[0],a0[1]), pkbf(a0[2],a0[3]), pkbf(a0[4],a0[5]), pkbf(a0[6],a0[7])); \
    fA1.u = make_uint4(pkbf(a1[0],a1[1]), pkbf(a1[2],a1[3]), pkbf(a1[4],a1[5]), pkbf(a1[6],a1[7])); \
    fA2.u = make_uint4(pkbf(a2[0],a2[1]), pkbf(a2[2],a2[3]), pkbf(a2[4],a2[5]), pkbf(a2[6],a2[7])); \
    U4 b0, b1, b2, b3, b4, b5;                                                       \
    b0.u = (B).b[0]; b1.u = (B).b[1]; b2.u = (B).b[2];                               \
    b3.u = (B).b[3]; b4.u = (B).b[4]; b5.u = (B).b[5];                               \
    acc##R##0 = MFMA32(fA0.s, b0.s, acc##R##0, 0, 0, 0);                             \
    acc##R##1 = MFMA32(fA0.s, b1.s, acc##R##1, 0, 0, 0);                             \
    acc##R##0 = MFMA32(fA1.s, b2.s, acc##R##0, 0, 0, 0);                             \
    acc##R##1 = MFMA32(fA1.s, b3.s, acc##R##1, 0, 0, 0);                             \
    acc##R##0 = MFMA32(fA2.s, b4.s, acc##R##0, 0, 0, 0);                             \
    acc##R##1 = MFMA32(fA2.s, b5.s, acc##R##1, 0, 0, 0);                             \
  }while(0)

  BSet Ba, Bb; YSet Ya0, Ya1, Yb0, Yb1;
  ldB(f0 + 0, Ba); ldY(0, Ya0, Ya1);
  ldB(f0 + 1, Bb); ldY(1, Yb0, Yb1);

#pragma unroll 1
  for (int s = 0; s < 32; s += 2){
    AGEN_MFMA(0, Ya0, Ba);
    AGEN_MFMA(1, Ya1, Ba);
    const int s2 = (s + 2 < 32) ? s + 2 : 31;
    ldB(f0 + s2, Ba); ldY(s2, Ya0, Ya1);
    AGEN_MFMA(0, Yb0, Bb);
    AGEN_MFMA(1, Yb1, Bb);
    const int s3 = (s + 3 < 32) ? s + 3 : 31;
    ldB(f0 + s3, Bb); ldY(s3, Yb0, Yb1);
  }
#undef AGEN_MFMA

  // ---- in-WG reduction over gq (3 barriers total) ----
  if (gq >= 2){
#pragma unroll
    for (int e = 0; e < 16; ++e){
      red[gq-2][ 0+e][lane] = acc00[e];
      red[gq-2][16+e][lane] = acc01[e];
      red[gq-2][32+e][lane] = acc10[e];
      red[gq-2][48+e][lane] = acc11[e];
    }
  }
  __syncthreads();
  if (gq < 2){
#pragma unroll
    for (int e = 0; e < 16; ++e){
      acc00[e] += red[gq][ 0+e][lane];
      acc01[e] += red[gq][16+e][lane];
      acc10[e] += red[gq][32+e][lane];
      acc11[e] += red[gq][48+e][lane];
    }
  }
  __syncthreads();
  if (gq == 1){
#pragma unroll
    for (int e = 0; e < 16; ++e){
      red[0][ 0+e][lane] = acc00[e];
      red[0][16+e][lane] = acc01[e];
      red[0][32+e][lane] = acc10[e];
      red[0][48+e][lane] = acc11[e];
    }
  }
  __syncthreads();
  if (gq == 0){
    float* mp = mixp + (size_t)fh * 1048576;
#pragma unroll
    for (int e = 0; e < 16; ++e){
      float v00 = acc00[e] + red[0][ 0+e][lane];
      float v01 = acc01[e] + red[0][16+e][lane];
      float v10 = acc10[e] + red[0][32+e][lane];
      float v11 = acc11[e] + red[0][48+e][lane];
      int rowm = (e & 3) + 8*(e >> 2) + 4*h;
      mp[(size_t)(pbase + rowm)*128      + nh*64 + pr]      = v00;
      mp[(size_t)(pbase + rowm)*128      + nh*64 + 32 + pr] = v01;
      mp[(size_t)(pbase + 32 + rowm)*128 + nh*64 + pr]      = v10;
      mp[(size_t)(pbase + 32 + rowm)*128 + nh*64 + 32 + pr] = v11;
    }
  }
}

// ---------------- MLP + final einsum + epilogue ----------------
__global__ __launch_bounds__(256, 1)
void mlp_final(const float* __restrict__ x, const float* __restrict__ y,
               const ushort_t* __restrict__ whfrag,
               const ushort_t* __restrict__ wffrag,
               const float* __restrict__ mixp, float* __restrict__ out){
  extern __shared__ char ldsm[];
  ushort_t* hw = (ushort_t*)ldsm;
  const int t = threadIdx.x;
  const long pbase = (long)blockIdx.x * 32;

  {  // load mix = sum of 2 partials -> act buf0 (bf16)
    int p = t >> 3, n0 = (t & 7) * 16;
    const float* src = mixp + (pbase + p)*128 + n0;
    int path = n0 >> 6, nn = n0 & 63;
    ushort_t* dst = hw + (path*2)*2176 + p*68 + nn;
#pragma unroll
    for (int q2 = 0; q2 < 16; ++q2){
      float v = src[q2] + src[q2 + 1048576];
      dst[q2] = f2bf(v);
    }
  }
  __syncthreads();

  const int w = t >> 6, lane = t & 63;
  const int path = w >> 1, ntw = w & 1;
  const int prow = lane & 31, h = lane >> 5;
  int cur = 0;

#pragma unroll
  for (int layer = 0; layer < 2; ++layer){
    const ushort_t* act = hw + (path*2 + cur)*2176;
    f32x16 acc;
#pragma unroll
    for (int r = 0; r < 16; ++r) acc[r] = 0.f;
#pragma unroll
    for (int c = 0; c < 4; ++c){
      int ab = prow*68 + c*16 + 4*h;
      ushort4 lo = *(const ushort4*)&act[ab];
      ushort4 hi = *(const ushort4*)&act[ab + 8];
      short8 av; av[0]=lo.x; av[1]=lo.y; av[2]=lo.z; av[3]=lo.w;
      av[4]=hi.x; av[5]=hi.y; av[6]=hi.z; av[7]=hi.w;
      short8 bv = *(const short8*)(whfrag + ((((layer*2 + path)*4 + c)*2 + ntw)*512 + lane*8));
      acc = MFMA32(av, bv, acc, 0, 0, 0);
    }
    ushort_t* nact = hw + (path*2 + (cur ^ 1))*2176;
#pragma unroll
    for (int r = 0; r < 16; ++r){
      int p = (r & 3) + 8*(r >> 2) + 4*h;
      nact[p*68 + ntw*32 + prow] = f2bf(tanh_fast(acc[r]));
    }
    cur ^= 1;
    __syncthreads();
  }

  {  // final einsum: o[p][n=l*64+f], N=192 -> each wave 3 n-tiles
    const ushort_t* act = hw + (path*2 + cur)*2176;
    ushort_t* ob = hw + 8704 + path*6272;
#pragma unroll
    for (int e = 0; e < 3; ++e){
      int ntf = ntw*3 + e;
      f32x16 acc;
#pragma unroll
      for (int r = 0; r < 16; ++r) acc[r] = 0.f;
#pragma unroll
      for (int c = 0; c < 4; ++c){
        int ab = prow*68 + c*16 + 4*h;
        ushort4 lo = *(const ushort4*)&act[ab];
        ushort4 hi = *(const ushort4*)&act[ab + 8];
        short8 av; av[0]=lo.x; av[1]=lo.y; av[2]=lo.z; av[3]=lo.w;
        av[4]=hi.x; av[5]=hi.y; av[6]=hi.z; av[7]=hi.w;
        short8 bv = *(const short8*)(wffrag + (((path*4 + c)*6 + ntf)*512 + lane*8));
        acc = MFMA32(av, bv, acc, 0, 0, 0);
      }
#pragma unroll
      for (int r = 0; r < 16; ++r){
        int p = (r & 3) + 8*(r >> 2) + 4*h;
        ob[p*196 + ntf*32 + prow] = f2bf(tanh_fast(acc[r]));
      }
    }
  }
  __syncthreads();

  const ushort_t* oxb = hw + 8704;
  const ushort_t* oyb = hw + 8704 + 6272;
#pragma unroll 1
  for (int rep = 0; rep < 8; ++rep){
    int idx = t + rep*256;
    int p = idx >> 6, fq = idx & 63;
    const float* xr = x + ((pbase + p)*64 + fq)*9;
    const float* yr = y + ((pbase + p)*64 + fq)*9;
    float xv[9], yv[9];
#pragma unroll
    for (int s = 0; s < 9; ++s){ xv[s] = xr[s]; yv[s] = yr[s]; }
    float c0 = xv[2]*yv[3] - xv[3]*yv[2];
    float c1 = xv[3]*yv[1] - xv[1]*yv[3];
    float c2 = xv[1]*yv[2] - xv[2]*yv[1];
    float gate = c0*yv[0] + c1*yv[1] + c2*yv[2];
    float ox0 = bf2f(oxb[p*196 + fq]);
    float ox1 = bf2f(oxb[p*196 + 64 + fq]);
    float ox2 = bf2f(oxb[p*196 + 128 + fq]);
    float oy0 = bf2f(oyb[p*196 + fq]);
    float oy1 = bf2f(oyb[p*196 + 64 + fq]);
    float oy2 = bf2f(oyb[p*196 + 128 + fq]);
    float* orow = out + ((pbase + p)*64 + fq)*9;
    orow[0] = ox0*xv[0]*gate + oy0*yv[0];
#pragma unroll
    for (int s = 1; s < 4; ++s) orow[s] = ox1*xv[s]*gate + oy1*yv[s];
#pragma unroll
    for (int s = 4; s < 9; ++s) orow[s] = ox2*xv[s]*gate + oy2*yv[s];
  }
}

extern "C" void kernel_launch(void* const* d_in, const int* in_sizes, int n_in,
                              void* d_out, int out_size, void* d_ws, size_t ws_size,
                              hipStream_t stream){
  (void)in_sizes; (void)n_in; (void)out_size; (void)ws_size;
  const float* x   = (const float*)d_in[0];
  const float* y   = (const float*)d_in[1];
  const float* wx0 = (const float*)d_in[2];
  const float* wy0 = (const float*)d_in[3];
  const float* wxh = (const float*)d_in[4];
  const float* wyh = (const float*)d_in[5];
  const float* wxf = (const float*)d_in[6];
  const float* wyf = (const float*)d_in[7];
  float* out = (float*)d_out;
  char* ws = (char*)d_ws;
  ushort_t* wfrag  = (ushort_t*)(ws);              //  3,145,728 B
  ushort_t* whfrag = (ushort_t*)(ws + 3145728);    //     32,768 B
  ushort_t* wffrag = (ushort_t*)(ws + 3178496);    //     49,152 B
  ushort_t* y2h    = (ushort_t*)(ws + 3227648);    // 12,582,912 B
  float* mixp      = (float*)(ws + 15810560);      // 2 x 4,194,304 B

  (void)hipFuncSetAttribute((const void*)mlp_final,
        hipFuncAttributeMaxDynamicSharedMemorySize, 43520);

  hipLaunchKernelGGL(bake_w0, dim3(768),   dim3(256), 0, stream, wx0, wy0, wfrag);
  hipLaunchKernelGGL(bake_wh, dim3(8),     dim3(256), 0, stream, wxh, wyh, whfrag);
  hipLaunchKernelGGL(bake_wf, dim3(12),    dim3(256), 0, stream, wxf, wyf, wffrag);
  hipLaunchKernelGGL(bake_y,  dim3(12288), dim3(256), 0, stream, y, y2h);
  hipLaunchKernelGGL(gemm5,   dim3(512),   dim3(256), 0, stream, x, y, y2h, wfrag, mixp);
  hipLaunchKernelGGL(mlp_final, dim3(256), dim3(256), 42496, stream, x, y, whfrag, wffrag, mixp, out);
}